// Round 17
// baseline (330.729 us; speedup 1.0000x reference)
//
#include <hip/hip_runtime.h>

#define IN_CH  256
#define HCC    256   // HEADS*OUT_CH
#define HEADS  4
#define OUTC   64
#define NEG_SLOPE 0.2f

#define NBUK   512    // dst buckets (rng = ceil(N/512) nodes each)
#define NBLK   64     // partition blocks (segment ~195B -> mostly-full lines)
#define SRC_BITS 17
#define SRC_MASK 0x1FFFF

using short8v = __attribute__((ext_vector_type(8))) short;
using f32x4   = __attribute__((ext_vector_type(4))) float;

__device__ __forceinline__ unsigned short f2bf(float f) {
    unsigned u = __float_as_uint(f);
    unsigned r = (u + 0x7fffu + ((u >> 16) & 1u)) >> 16;  // RNE
    return (unsigned short)r;
}
__device__ __forceinline__ float bf2f(unsigned short b) {
    return __uint_as_float((unsigned)b << 16);
}
__device__ __forceinline__ int buk_of(int dst, unsigned M) {
    unsigned s = (unsigned)(((unsigned long long)(unsigned)dst * M) >> 32);
    return (s >= NBUK) ? (NBUK - 1) : (int)s;
}
__device__ __forceinline__ void gload_lds16(const unsigned short* g,
                                            unsigned short* lds) {
    __builtin_amdgcn_global_load_lds(
        (const __attribute__((address_space(1))) unsigned*)g,
        (__attribute__((address_space(3))) unsigned*)lds, 16, 0, 0);
}

// ---------------------------------------------------------------------------
// Kernel 0a: W [K=256][N=256] fp32 -> WT [N][K] bf16 (tiny, one-time)
// ---------------------------------------------------------------------------
__global__ void k_wt(const float* __restrict__ W,
                     unsigned short* __restrict__ WT) {
    int n = blockIdx.x;
    int k = threadIdx.x;
    WT[n * IN_CH + k] = f2bf(W[(size_t)k * HCC + n]);
}

// ---------------------------------------------------------------------------
// Kernel 0b: X fp32 -> bf16, streaming (~25us at full BW). Moves the
// conversion OUT of the gemm's latency-critical K-loop and leaves the 51MB
// bf16 X L3-resident for the gemm's async A loads.
// ---------------------------------------------------------------------------
__global__ __launch_bounds__(256) void k_xb(const float* __restrict__ X,
                                            unsigned short* __restrict__ XB,
                                            long nquad) {
    long i = (long)blockIdx.x * 256 + threadIdx.x;
    long stride = (long)gridDim.x * 256;
    for (; i < nquad; i += stride) {
        float4 v = *(const float4*)(X + i * 4);
        ushort4 b;
        b.x = f2bf(v.x); b.y = f2bf(v.y);
        b.z = f2bf(v.z); b.w = f2bf(v.w);
        *(ushort4*)(XB + i * 4) = b;
    }
}

// ---------------------------------------------------------------------------
// Kernel 1 (fused, BM=64, BK=64, fully-async staging): heterogeneous grid.
//   blocks [0, ngemm):          MFMA GEMM tile 64x256 + fused att logits
//   blocks [ngemm, ngemm+NBLK): dst-bucket histogram (CSR sweep 1)
// K-loop is pure {10x global_load_lds, barrier, 32 MFMA, barrier} — zero
// VALU staging (m97 structure). A and B both use linear LDS dest +
// XOR-swizzled 16B-chunk SOURCE; reads de-swizzle with chunk^(r16&7) ->
// 2-way banks (free).
// ---------------------------------------------------------------------------
__global__ __launch_bounds__(256) void k_gemm_pcnt(
    const unsigned short* __restrict__ XB, const unsigned short* __restrict__ WT,
    const float* __restrict__ ASRC, const float* __restrict__ ADST,
    unsigned short* __restrict__ XLB, float* __restrict__ a_s,
    float* __restrict__ a_d, int N, int ngemm,
    const int* __restrict__ ei, int* __restrict__ pcnt2d, int E, unsigned M) {
    __shared__ __align__(16) unsigned short Asl[64 * 64];  // linear [m][k]
    __shared__ __align__(16) unsigned short Bs[256 * 64];  // linear [n][k]
    __shared__ int hbuk[NBUK];

    if (blockIdx.x >= ngemm) {
        // ---- CSR sweep 1: per-(bucket,block) counts via LDS histogram ----
        int bid = blockIdx.x - ngemm;
        int t = threadIdx.x;
        for (int k = t; k < NBUK; k += 256) hbuk[k] = 0;
        __syncthreads();
        int chunk = (E + NBLK - 1) / NBLK;
        int e0 = bid * chunk;
        int e1 = e0 + chunk;
        if (e1 > E) e1 = E;
        for (int i = e0 + t; i < e1; i += 256)
            atomicAdd(&hbuk[buk_of(ei[E + i], M)], 1);
        __syncthreads();
        for (int k = t; k < NBUK; k += 256)
            pcnt2d[k * NBLK + bid] = hbuk[k];
        return;
    }

    // ---- GEMM tile: 64 rows x 256 cols, BK=64, async staging ----
    const int tid = threadIdx.x;
    const int lane = tid & 63;
    const int wid = tid >> 6;
    const int m0 = blockIdx.x * 64;
    const int r16 = lane & 15;
    const int g = lane >> 4;
    const int l8 = lane >> 3;        // 0..7
    const int cs = (lane & 7) ^ l8;  // swizzled source chunk (A and B alike)

    // hoisted per-lane source pointers
    int agr0 = m0 + wid * 16 + (lane >> 3);        // A issue 0 row
    int agr1 = agr0 + 8;                           // A issue 1 row
    if (agr0 >= N) agr0 = 0;                       // clamp OOB (discarded)
    if (agr1 >= N) agr1 = 0;
    const unsigned short* aptr0 = XB + (size_t)agr0 * IN_CH + cs * 8;
    const unsigned short* aptr1 = XB + (size_t)agr1 * IN_CH + cs * 8;
    const unsigned short* bptr[8];
#pragma unroll
    for (int i = 0; i < 8; ++i) {
        int row = wid * 64 + i * 8 + l8;
        bptr[i] = WT + (size_t)row * IN_CH + cs * 8;
    }

    f32x4 acc[4][4];
    const f32x4 z = {0.f, 0.f, 0.f, 0.f};
#pragma unroll
    for (int m = 0; m < 4; ++m)
#pragma unroll
        for (int n = 0; n < 4; ++n) acc[m][n] = z;

    for (int kb = 0; kb < IN_CH; kb += 64) {
        // B: 8 issues/wave of 1024B direct global->LDS
#pragma unroll
        for (int i = 0; i < 8; ++i)
            gload_lds16(bptr[i] + kb, &Bs[(wid * 64 + i * 8) * 64]);
        // A: 2 issues/wave of 1024B direct global->LDS
        gload_lds16(aptr0 + kb, &Asl[(wid * 16) * 64]);
        gload_lds16(aptr1 + kb, &Asl[(wid * 16 + 8) * 64]);
        __syncthreads();   // drains vmcnt (gload_lds) before LDS reads
#pragma unroll
        for (int ks = 0; ks < 2; ++ks) {
            short8v af[4], bf[4];
            int cksw = (ks * 4 + g) ^ (r16 & 7);  // de-swizzle on read
#pragma unroll
            for (int m = 0; m < 4; ++m)
                af[m] = *(const short8v*)&Asl[(m * 16 + r16) * 64 + cksw * 8];
#pragma unroll
            for (int n = 0; n < 4; ++n) {
                int row = wid * 64 + n * 16 + r16;
                bf[n] = *(const short8v*)&Bs[row * 64 + cksw * 8];
            }
#pragma unroll
            for (int m = 0; m < 4; ++m)
#pragma unroll
                for (int n = 0; n < 4; ++n)
                    acc[m][n] = __builtin_amdgcn_mfma_f32_16x16x32_bf16(
                        af[m], bf[n], acc[m][n], 0, 0, 0);
        }
        __syncthreads();
    }

    const int h = wid;
    float asc[4], adc[4];
#pragma unroll
    for (int n = 0; n < 4; ++n) {
        asc[n] = ASRC[h * OUTC + n * 16 + r16];
        adc[n] = ADST[h * OUTC + n * 16 + r16];
    }

    // att logits from fp32 acc (D frag: col=lane&15, row=(lane>>4)*4+j)
#pragma unroll
    for (int m = 0; m < 4; ++m) {
#pragma unroll
        for (int j = 0; j < 4; ++j) {
            int row = m0 + m * 16 + g * 4 + j;
            float ds = 0.f, dd = 0.f;
#pragma unroll
            for (int n = 0; n < 4; ++n) {
                ds = fmaf(acc[m][n][j], asc[n], ds);
                dd = fmaf(acc[m][n][j], adc[n], dd);
            }
#pragma unroll
            for (int o = 1; o < 16; o <<= 1) {
                ds += __shfl_xor(ds, o);
                dd += __shfl_xor(dd, o);
            }
            if (row < N && r16 == 0) {
                a_s[(size_t)row * HEADS + h] = ds;
                a_d[(size_t)row * HEADS + h] = dd;
            }
        }
    }

    // C repack: bf16 acc -> swizzled LDS (overlay Bs; final K-loop barrier
    // guarantees Bs reads done) -> coalesced 512B row stores. [R15-verified]
    unsigned short* Cs = Bs;  // 64 rows x 256 cols x 2B = 32KB exactly
#pragma unroll
    for (int m = 0; m < 4; ++m) {
#pragma unroll
        for (int j = 0; j < 4; ++j) {
            int row = m * 16 + g * 4 + j;
            int sx = row & 7;  // 8B-chunk XOR swizzle
#pragma unroll
            for (int n = 0; n < 4; ++n) {
                int col = wid * 64 + n * 16 + r16;
                int sub = col >> 2, wi = col & 3;
                Cs[row * 256 + ((sub ^ sx) << 2) + wi] = f2bf(acc[m][n][j]);
            }
        }
    }
    __syncthreads();
#pragma unroll
    for (int it = 0; it < 16; ++it) {
        int row = wid + it * 4;
        int gr = m0 + row;
        if (gr < N) {
            int sx = row & 7;
            uint2 v = *(const uint2*)&Cs[row * 256 + ((lane ^ sx) << 2)];
            *(uint2*)(XLB + (size_t)gr * HCC + lane * 4) = v;
        }
    }
}

// ---------------------------------------------------------------------------
// CSR build v6.2 (R12-measured ~37us tail): scan + partition + per-bucket
// finalize. NBLK=64.
// ---------------------------------------------------------------------------

// scan of the NBUK*NBLK (bucket-major) counts -> base2d + per-bucket pbase
__global__ __launch_bounds__(1024) void k_pscan(const int* __restrict__ pcnt2d,
                                                int* __restrict__ base2d,
                                                int* __restrict__ pbase,
                                                int E) {
    __shared__ int s[1024];
    const int PT = (NBUK * NBLK) / 1024;  // 32 per thread
    int t = threadIdx.x;
    int c[PT];
    int sum = 0;
#pragma unroll
    for (int i = 0; i < PT; ++i) {
        c[i] = pcnt2d[t * PT + i];
        sum += c[i];
    }
    s[t] = sum;
    __syncthreads();
    for (int off = 1; off < 1024; off <<= 1) {
        int x = (t >= off) ? s[t - off] : 0;
        __syncthreads();
        s[t] += x;
        __syncthreads();
    }
    int run = s[t] - sum;  // exclusive
#pragma unroll
    for (int i = 0; i < PT; ++i) {
        int j = t * PT + i;
        base2d[j] = run;
        if ((j & (NBLK - 1)) == 0) pbase[j / NBLK] = run;
        run += c[i];
    }
    if (t == 0) pbase[NBUK] = E;
}

// sweep 2: write packed edges into exact block-private (bucket,block) segs
__global__ __launch_bounds__(256) void k_part2(const int* __restrict__ ei,
                                               const int* __restrict__ base2d,
                                               unsigned* __restrict__ pedges,
                                               int E, unsigned M, int rng) {
    __shared__ int cur[NBUK];
    int t = threadIdx.x;
    for (int k = t; k < NBUK; k += 256)
        cur[k] = base2d[k * NBLK + blockIdx.x];
    __syncthreads();
    int chunk = (E + NBLK - 1) / NBLK;
    int e0 = blockIdx.x * chunk;
    int e1 = e0 + chunk;
    if (e1 > E) e1 = E;
    for (int i = e0 + t; i < e1; i += 256) {
        int src = ei[i];
        int dst = ei[E + i];
        int s = buk_of(dst, M);
        int pos = atomicAdd(&cur[s], 1);  // LDS atomic only
        pedges[pos] = ((unsigned)(dst - s * rng) << SRC_BITS) | (unsigned)src;
    }
}

// per-bucket finalize: LDS histogram + scan -> rowptr, self-loops, eid.
__global__ __launch_bounds__(256) void k_fin(const int* __restrict__ pbase,
                                             const unsigned* __restrict__ pedges,
                                             int* __restrict__ rowptr,
                                             int* __restrict__ eid,
                                             int N, int rng) {
    __shared__ int cntL[256];
    __shared__ int scanL[256];
    __shared__ int fillL[256];
    int k = blockIdx.x;
    int t = threadIdx.x;
    int lo = k * rng;
    if (lo >= N) return;
    int nloc = N - lo;
    if (nloc > rng) nloc = rng;
    int p0 = pbase[k];
    int cnt = pbase[k + 1] - p0;
    cntL[t] = 0;
    __syncthreads();
    for (int i = t; i < cnt; i += 256)
        atomicAdd(&cntL[pedges[p0 + i] >> SRC_BITS], 1);
    __syncthreads();
    int own = (t < nloc) ? cntL[t] + 1 : 0;  // +1 self-loop
    scanL[t] = own;
    __syncthreads();
    for (int off = 1; off < 256; off <<= 1) {
        int x = (t >= off) ? scanL[t - off] : 0;
        __syncthreads();
        scanL[t] += x;
        __syncthreads();
    }
    int excl = scanL[t] - own;
    int gbase = p0 + lo;  // edge prefix + self-loop prefix
    if (t < nloc) {
        rowptr[lo + t] = gbase + excl;
        if (lo + t == N - 1) rowptr[N] = gbase + excl + own;
        eid[gbase + excl] = lo + t;  // self-loop first
        fillL[t] = excl + 1;
    }
    __syncthreads();
    for (int i = t; i < cnt; i += 256) {
        unsigned pk = pedges[p0 + i];
        int dl = (int)(pk >> SRC_BITS);
        int pos = atomicAdd(&fillL[dl], 1);
        eid[gbase + pos] = (int)(pk & SRC_MASK);
    }
}

// ---------------------------------------------------------------------------
// Kernel 3: per-dst softmax + aggregation. One WAVE per node, lane owns 4
// channels. 8-deep edge unroll. No max subtraction (logits O(8), fp32 exp
// safe).
// ---------------------------------------------------------------------------
__global__ __launch_bounds__(256) void k_agg(const int* __restrict__ rowptr,
                                             const int* __restrict__ eid,
                                             const float* __restrict__ a_s,
                                             const float* __restrict__ a_d,
                                             const unsigned short* __restrict__ XLB,
                                             const float* __restrict__ BIAS,
                                             float* __restrict__ OUT, int N) {
    int wid = threadIdx.x >> 6;
    int lane = threadIdx.x & 63;
    int n = blockIdx.x * 4 + wid;
    if (n >= N) return;
    int h = lane >> 4;
    int s0 = rowptr[n];
    int s1 = rowptr[n + 1];
    float adn = a_d[(size_t)n * HEADS + h];
    float s = 0.f;
    float acc0 = 0.f, acc1 = 0.f, acc2 = 0.f, acc3 = 0.f;

    int e = s0;
    for (; e + 8 <= s1; e += 8) {
        int idx[8];
#pragma unroll
        for (int j = 0; j < 8; ++j) idx[j] = eid[e + j];
        float l[8];
#pragma unroll
        for (int j = 0; j < 8; ++j) l[j] = a_s[(size_t)idx[j] * HEADS + h] + adn;
        ushort4 xv[8];
#pragma unroll
        for (int j = 0; j < 8; ++j)
            xv[j] = *(const ushort4*)(XLB + (size_t)idx[j] * HCC + lane * 4);
#pragma unroll
        for (int j = 0; j < 8; ++j) {
            float lj = fmaxf(l[j], NEG_SLOPE * l[j]);
            float p = __expf(lj);
            s += p;
            acc0 = fmaf(p, bf2f(xv[j].x), acc0);
            acc1 = fmaf(p, bf2f(xv[j].y), acc1);
            acc2 = fmaf(p, bf2f(xv[j].z), acc2);
            acc3 = fmaf(p, bf2f(xv[j].w), acc3);
        }
    }
    for (; e + 4 <= s1; e += 4) {
        int idx[4];
#pragma unroll
        for (int j = 0; j < 4; ++j) idx[j] = eid[e + j];
        float l[4];
#pragma unroll
        for (int j = 0; j < 4; ++j) l[j] = a_s[(size_t)idx[j] * HEADS + h] + adn;
        ushort4 xv[4];
#pragma unroll
        for (int j = 0; j < 4; ++j)
            xv[j] = *(const ushort4*)(XLB + (size_t)idx[j] * HCC + lane * 4);
#pragma unroll
        for (int j = 0; j < 4; ++j) {
            float lj = fmaxf(l[j], NEG_SLOPE * l[j]);
            float p = __expf(lj);
            s += p;
            acc0 = fmaf(p, bf2f(xv[j].x), acc0);
            acc1 = fmaf(p, bf2f(xv[j].y), acc1);
            acc2 = fmaf(p, bf2f(xv[j].z), acc2);
            acc3 = fmaf(p, bf2f(xv[j].w), acc3);
        }
    }
    for (; e < s1; ++e) {
        int src = eid[e];
        float l = a_s[(size_t)src * HEADS + h] + adn;
        l = fmaxf(l, NEG_SLOPE * l);
        float p = __expf(l);
        ushort4 xv = *(const ushort4*)(XLB + (size_t)src * HCC + lane * 4);
        s += p;
        acc0 = fmaf(p, bf2f(xv.x), acc0);
        acc1 = fmaf(p, bf2f(xv.y), acc1);
        acc2 = fmaf(p, bf2f(xv.z), acc2);
        acc3 = fmaf(p, bf2f(xv.w), acc3);
    }

    float inv = 1.f / (s + 1e-16f);
    float4 b = *(const float4*)(BIAS + lane * 4);
    float4 o;
    o.x = acc0 * inv + b.x;
    o.y = acc1 * inv + b.y;
    o.z = acc2 * inv + b.z;
    o.w = acc3 * inv + b.w;
    *(float4*)(OUT + (size_t)n * HCC + lane * 4) = o;
}

// ---------------------------------------------------------------------------
extern "C" void kernel_launch(void* const* d_in, const int* in_sizes, int n_in,
                              void* d_out, int out_size, void* d_ws,
                              size_t ws_size, hipStream_t stream) {
    const float* X = (const float*)d_in[0];
    const int* EI = (const int*)d_in[1];
    const float* W = (const float*)d_in[2];
    const float* ASRC = (const float*)d_in[3];
    const float* ADST = (const float*)d_in[4];
    const float* BIAS = (const float*)d_in[5];
    float* OUT = (float*)d_out;

    const int N = in_sizes[0] / IN_CH;
    const int E = in_sizes[1] / 2;
    const int ET = E + N;
    const int rng = (N + NBUK - 1) / NBUK;
    const unsigned M = (unsigned)(((1ULL << 32) + rng - 1) / (unsigned)rng);

    // workspace layout (all 256B aligned)
    char* w = (char*)d_ws;
    auto align = [](size_t x) { return (x + 255) & ~(size_t)255; };
    size_t o = 0;
    unsigned short* xlb = (unsigned short*)(w + o); o += align((size_t)N * HCC * 2);
    unsigned short* xb = (unsigned short*)(w + o);  o += align((size_t)N * IN_CH * 2);
    unsigned short* wt = (unsigned short*)(w + o);  o += align((size_t)IN_CH * HCC * 2);
    float* a_s = (float*)(w + o); o += align((size_t)N * HEADS * 4);
    float* a_d = (float*)(w + o); o += align((size_t)N * HEADS * 4);
    int* rowptr = (int*)(w + o);  o += align((size_t)(N + 1) * 4);
    int* eid = (int*)(w + o);     o += align((size_t)ET * 4);
    unsigned* pedges = (unsigned*)(w + o); o += align((size_t)E * 4);
    int* pcnt2d = (int*)(w + o);  o += align((size_t)NBUK * NBLK * 4);
    int* base2d = (int*)(w + o);  o += align((size_t)NBUK * NBLK * 4);
    int* pbase = (int*)(w + o);   o += align((NBUK + 1) * 4);

    // 0. W -> WT (bf16, transposed); X -> bf16 (streaming)
    k_wt<<<HCC, IN_CH, 0, stream>>>(W, wt);
    long nquad = (long)N * IN_CH / 4;
    int gxb = (int)((nquad + 255) / 256);
    if (gxb > 2048) gxb = 2048;
    k_xb<<<gxb, 256, 0, stream>>>(X, xb, nquad);

    // 1. fused: MFMA GEMM 64x256 BK=64 async (+att logits) || CSR histogram
    int ngemm = (N + 63) / 64;
    k_gemm_pcnt<<<ngemm + NBLK, 256, 0, stream>>>(xb, wt, ASRC, ADST, xlb,
                                                  a_s, a_d, N, ngemm, EI,
                                                  pcnt2d, E, M);

    // 2. CSR build v6.2
    k_pscan<<<1, 1024, 0, stream>>>(pcnt2d, base2d, pbase, E);
    k_part2<<<NBLK, 256, 0, stream>>>(EI, base2d, pedges, E, M, rng);
    k_fin<<<NBUK, 256, 0, stream>>>(pbase, pedges, rowptr, eid, N, rng);

    // 3. per-dst softmax + weighted aggregation (one wave per node)
    k_agg<<<(N + 3) / 4, 256, 0, stream>>>(rowptr, eid, a_s, a_d, xlb, BIAS,
                                           OUT, N);
}

// Round 18
// 325.384 us; speedup vs baseline: 1.0164x; 1.0164x over previous
//
#include <hip/hip_runtime.h>

#define IN_CH  256
#define HCC    256   // HEADS*OUT_CH
#define HEADS  4
#define OUTC   64
#define NEG_SLOPE 0.2f

#define NBUK   512    // dst buckets (rng = ceil(N/512) nodes each)
#define NBLK   64     // partition blocks (segment ~195B -> mostly-full lines)
#define SRC_BITS 17
#define SRC_MASK 0x1FFFF

using short8v = __attribute__((ext_vector_type(8))) short;
using f32x4   = __attribute__((ext_vector_type(4))) float;

__device__ __forceinline__ unsigned short f2bf(float f) {
    unsigned u = __float_as_uint(f);
    unsigned r = (u + 0x7fffu + ((u >> 16) & 1u)) >> 16;  // RNE
    return (unsigned short)r;
}
__device__ __forceinline__ float bf2f(unsigned short b) {
    return __uint_as_float((unsigned)b << 16);
}
__device__ __forceinline__ int buk_of(int dst, unsigned M) {
    unsigned s = (unsigned)(((unsigned long long)(unsigned)dst * M) >> 32);
    return (s >= NBUK) ? (NBUK - 1) : (int)s;
}
__device__ __forceinline__ void gload_lds16(const unsigned short* g,
                                            unsigned short* lds) {
    __builtin_amdgcn_global_load_lds(
        (const __attribute__((address_space(1))) unsigned*)g,
        (__attribute__((address_space(3))) unsigned*)lds, 16, 0, 0);
}

// ---------------------------------------------------------------------------
// Kernel 0a: W [K=256][N=256] fp32 -> WT [N][K] bf16 (tiny, one-time)
// ---------------------------------------------------------------------------
__global__ void k_wt(const float* __restrict__ W,
                     unsigned short* __restrict__ WT) {
    int n = blockIdx.x;
    int k = threadIdx.x;
    WT[n * IN_CH + k] = f2bf(W[(size_t)k * HCC + n]);
}

// ---------------------------------------------------------------------------
// Kernel 0b (fused): blocks [0,gxb) stream-convert X fp32->bf16;
// blocks [gxb, gxb+NBLK) do the CSR dst-bucket histogram (rides the idle
// VALU/fabric of the streaming kernel).
// ---------------------------------------------------------------------------
__global__ __launch_bounds__(256) void k_xb_pcnt(const float* __restrict__ X,
                                                 unsigned short* __restrict__ XB,
                                                 long nquad, int gxb,
                                                 const int* __restrict__ ei,
                                                 int* __restrict__ pcnt2d,
                                                 int E, unsigned M) {
    __shared__ int hbuk[NBUK];
    if (blockIdx.x >= gxb) {
        int bid = blockIdx.x - gxb;
        int t = threadIdx.x;
        for (int k = t; k < NBUK; k += 256) hbuk[k] = 0;
        __syncthreads();
        int chunk = (E + NBLK - 1) / NBLK;
        int e0 = bid * chunk;
        int e1 = e0 + chunk;
        if (e1 > E) e1 = E;
        for (int i = e0 + t; i < e1; i += 256)
            atomicAdd(&hbuk[buk_of(ei[E + i], M)], 1);
        __syncthreads();
        for (int k = t; k < NBUK; k += 256)
            pcnt2d[k * NBLK + bid] = hbuk[k];
        return;
    }
    long i = (long)blockIdx.x * 256 + threadIdx.x;
    long stride = (long)gxb * 256;
    for (; i < nquad; i += stride) {
        float4 v = *(const float4*)(X + i * 4);
        ushort4 b;
        b.x = f2bf(v.x); b.y = f2bf(v.y);
        b.z = f2bf(v.z); b.w = f2bf(v.w);
        *(ushort4*)(XB + i * 4) = b;
    }
}

// ---------------------------------------------------------------------------
// Kernel 1: PERSISTENT GEMM. 256 blocks x 512 thr (8 waves, 2/SIMD),
// LDS = WT entire (128KB, staged ONCE, XOR-chunk swizzled) + 16KB A tile.
// Grid-strides over 3125 m-tiles (32 rows): {2 async A issues/wave, barrier,
// 32 MFMA/wave over full K=256, att-logit fuse, C repack via dead A buf,
// coalesced row stores}. Kills the per-block W re-staging that capped five
// prior gemm variants at ~125us (R15: occ 14.6%, all pipes idle).
// Wave w: rows (w>>2)*16..+15, cols (w&3)*64..+63 (head = w&3).
// Swizzle: LDS[row][slot] = src[row][slot ^ (row&15)]; read slot =
// (ks*4+g) ^ r16 -> 2-way banks.
// ---------------------------------------------------------------------------
__global__ __launch_bounds__(512) void k_gemm_pers(
    const unsigned short* __restrict__ XB, const unsigned short* __restrict__ WT,
    const float* __restrict__ ASRC, const float* __restrict__ ADST,
    unsigned short* __restrict__ XLB, float* __restrict__ a_s,
    float* __restrict__ a_d, int N, int ntiles) {
    __shared__ __align__(16) unsigned short Bs[256 * 256];  // 128 KB: all WT
    __shared__ __align__(16) unsigned short Asl[32 * 256];  // 16 KB A tile

    const int tid = threadIdx.x;
    const int lane = tid & 63;
    const int wid = tid >> 6;        // 0..7
    const int r16 = lane & 15;
    const int g = lane >> 4;         // 0..3
    const int mh = wid >> 2;         // 0..1: row half
    const int cg = wid & 3;          // 0..3: col group == head
    const int l2r = lane >> 5;       // 0..1: row within a 2-row issue
    const int c31 = lane & 31;       // chunk slot within row

    // one-time B stage: 16 issues/wave x 1KB (2 rows of 512B each)
#pragma unroll
    for (int i = 0; i < 16; ++i) {
        int r0 = wid * 32 + i * 2;               // wave-uniform
        int row = r0 + l2r;
        int cs = c31 ^ (row & 15);               // pre-swizzled source chunk
        gload_lds16(WT + (size_t)row * IN_CH + cs * 8, &Bs[r0 * 256]);
    }

    float asc[4], adc[4];
#pragma unroll
    for (int n = 0; n < 4; ++n) {
        asc[n] = ASRC[cg * OUTC + n * 16 + r16];
        adc[n] = ADST[cg * OUTC + n * 16 + r16];
    }
    __syncthreads();   // B resident

    const f32x4 z = {0.f, 0.f, 0.f, 0.f};
    for (int tile = blockIdx.x; tile < ntiles; tile += gridDim.x) {
        int t32 = tile * 32;
        // stage A: 2 issues/wave
#pragma unroll
        for (int i = 0; i < 2; ++i) {
            int r0 = wid * 4 + i * 2;            // wave-uniform
            int row = r0 + l2r;
            int grow = t32 + row;
            if (grow >= N) grow = 0;
            int cs = c31 ^ (row & 15);
            gload_lds16(XB + (size_t)grow * IN_CH + cs * 8, &Asl[r0 * 256]);
        }
        __syncthreads();   // A ready

        f32x4 acc[4] = {z, z, z, z};
#pragma unroll
        for (int ks = 0; ks < 8; ++ks) {
            int slot = (ks * 4 + g) ^ r16;       // de-swizzle
            short8v af = *(const short8v*)&Asl[(mh * 16 + r16) * 256 + slot * 8];
#pragma unroll
            for (int n = 0; n < 4; ++n) {
                int row = cg * 64 + n * 16 + r16;
                short8v bf = *(const short8v*)&Bs[row * 256 + slot * 8];
                acc[n] = __builtin_amdgcn_mfma_f32_16x16x32_bf16(
                    af, bf, acc[n], 0, 0, 0);
            }
        }

        // att logits from fp32 acc (D frag: col=lane&15, row=(lane>>4)*4+j)
#pragma unroll
        for (int j = 0; j < 4; ++j) {
            int grow = t32 + mh * 16 + g * 4 + j;
            float ds = 0.f, dd = 0.f;
#pragma unroll
            for (int n = 0; n < 4; ++n) {
                ds = fmaf(acc[n][j], asc[n], ds);
                dd = fmaf(acc[n][j], adc[n], dd);
            }
#pragma unroll
            for (int o = 1; o < 16; o <<= 1) {
                ds += __shfl_xor(ds, o);
                dd += __shfl_xor(dd, o);
            }
            if (grow < N && r16 == 0) {
                a_s[(size_t)grow * HEADS + cg] = ds;
                a_d[(size_t)grow * HEADS + cg] = dd;
            }
        }
        __syncthreads();   // all A reads done -> A buf reusable as C

        // C repack into Asl (16KB == 32x256 bf16 tile), 8B-chunk XOR swizzle
#pragma unroll
        for (int j = 0; j < 4; ++j) {
            int row = mh * 16 + g * 4 + j;
            int sx = row & 7;
#pragma unroll
            for (int n = 0; n < 4; ++n) {
                int col = cg * 64 + n * 16 + r16;
                int sub = col >> 2, wi = col & 3;
                Asl[row * 256 + ((sub ^ sx) << 2) + wi] = f2bf(acc[n][j]);
            }
        }
        __syncthreads();
        // coalesced stores: 1 row (512B) per wave-instr, 4 rows/wave
#pragma unroll
        for (int it = 0; it < 4; ++it) {
            int row = wid + it * 8;
            int gr = t32 + row;
            if (gr < N) {
                int sx = row & 7;
                uint2 v = *(const uint2*)&Asl[row * 256 + ((lane ^ sx) << 2)];
                *(uint2*)(XLB + (size_t)gr * HCC + lane * 4) = v;
            }
        }
        __syncthreads();   // store reads done before next tile's A stage
    }
}

// ---------------------------------------------------------------------------
// CSR build v6.2 (R12-measured ~37us tail): scan + partition + per-bucket
// finalize. NBLK=64.
// ---------------------------------------------------------------------------

__global__ __launch_bounds__(1024) void k_pscan(const int* __restrict__ pcnt2d,
                                                int* __restrict__ base2d,
                                                int* __restrict__ pbase,
                                                int E) {
    __shared__ int s[1024];
    const int PT = (NBUK * NBLK) / 1024;  // 32 per thread
    int t = threadIdx.x;
    int c[PT];
    int sum = 0;
#pragma unroll
    for (int i = 0; i < PT; ++i) {
        c[i] = pcnt2d[t * PT + i];
        sum += c[i];
    }
    s[t] = sum;
    __syncthreads();
    for (int off = 1; off < 1024; off <<= 1) {
        int x = (t >= off) ? s[t - off] : 0;
        __syncthreads();
        s[t] += x;
        __syncthreads();
    }
    int run = s[t] - sum;  // exclusive
#pragma unroll
    for (int i = 0; i < PT; ++i) {
        int j = t * PT + i;
        base2d[j] = run;
        if ((j & (NBLK - 1)) == 0) pbase[j / NBLK] = run;
        run += c[i];
    }
    if (t == 0) pbase[NBUK] = E;
}

__global__ __launch_bounds__(256) void k_part2(const int* __restrict__ ei,
                                               const int* __restrict__ base2d,
                                               unsigned* __restrict__ pedges,
                                               int E, unsigned M, int rng) {
    __shared__ int cur[NBUK];
    int t = threadIdx.x;
    for (int k = t; k < NBUK; k += 256)
        cur[k] = base2d[k * NBLK + blockIdx.x];
    __syncthreads();
    int chunk = (E + NBLK - 1) / NBLK;
    int e0 = blockIdx.x * chunk;
    int e1 = e0 + chunk;
    if (e1 > E) e1 = E;
    for (int i = e0 + t; i < e1; i += 256) {
        int src = ei[i];
        int dst = ei[E + i];
        int s = buk_of(dst, M);
        int pos = atomicAdd(&cur[s], 1);  // LDS atomic only
        pedges[pos] = ((unsigned)(dst - s * rng) << SRC_BITS) | (unsigned)src;
    }
}

__global__ __launch_bounds__(256) void k_fin(const int* __restrict__ pbase,
                                             const unsigned* __restrict__ pedges,
                                             int* __restrict__ rowptr,
                                             int* __restrict__ eid,
                                             int N, int rng) {
    __shared__ int cntL[256];
    __shared__ int scanL[256];
    __shared__ int fillL[256];
    int k = blockIdx.x;
    int t = threadIdx.x;
    int lo = k * rng;
    if (lo >= N) return;
    int nloc = N - lo;
    if (nloc > rng) nloc = rng;
    int p0 = pbase[k];
    int cnt = pbase[k + 1] - p0;
    cntL[t] = 0;
    __syncthreads();
    for (int i = t; i < cnt; i += 256)
        atomicAdd(&cntL[pedges[p0 + i] >> SRC_BITS], 1);
    __syncthreads();
    int own = (t < nloc) ? cntL[t] + 1 : 0;  // +1 self-loop
    scanL[t] = own;
    __syncthreads();
    for (int off = 1; off < 256; off <<= 1) {
        int x = (t >= off) ? scanL[t - off] : 0;
        __syncthreads();
        scanL[t] += x;
        __syncthreads();
    }
    int excl = scanL[t] - own;
    int gbase = p0 + lo;  // edge prefix + self-loop prefix
    if (t < nloc) {
        rowptr[lo + t] = gbase + excl;
        if (lo + t == N - 1) rowptr[N] = gbase + excl + own;
        eid[gbase + excl] = lo + t;  // self-loop first
        fillL[t] = excl + 1;
    }
    __syncthreads();
    for (int i = t; i < cnt; i += 256) {
        unsigned pk = pedges[p0 + i];
        int dl = (int)(pk >> SRC_BITS);
        int pos = atomicAdd(&fillL[dl], 1);
        eid[gbase + pos] = (int)(pk & SRC_MASK);
    }
}

// ---------------------------------------------------------------------------
// Kernel 3: per-dst softmax + aggregation. One WAVE per node, lane owns 4
// channels. 8-deep edge unroll. No max subtraction (logits O(8), fp32 exp
// safe).
// ---------------------------------------------------------------------------
__global__ __launch_bounds__(256) void k_agg(const int* __restrict__ rowptr,
                                             const int* __restrict__ eid,
                                             const float* __restrict__ a_s,
                                             const float* __restrict__ a_d,
                                             const unsigned short* __restrict__ XLB,
                                             const float* __restrict__ BIAS,
                                             float* __restrict__ OUT, int N) {
    int wid = threadIdx.x >> 6;
    int lane = threadIdx.x & 63;
    int n = blockIdx.x * 4 + wid;
    if (n >= N) return;
    int h = lane >> 4;
    int s0 = rowptr[n];
    int s1 = rowptr[n + 1];
    float adn = a_d[(size_t)n * HEADS + h];
    float s = 0.f;
    float acc0 = 0.f, acc1 = 0.f, acc2 = 0.f, acc3 = 0.f;

    int e = s0;
    for (; e + 8 <= s1; e += 8) {
        int idx[8];
#pragma unroll
        for (int j = 0; j < 8; ++j) idx[j] = eid[e + j];
        float l[8];
#pragma unroll
        for (int j = 0; j < 8; ++j) l[j] = a_s[(size_t)idx[j] * HEADS + h] + adn;
        ushort4 xv[8];
#pragma unroll
        for (int j = 0; j < 8; ++j)
            xv[j] = *(const ushort4*)(XLB + (size_t)idx[j] * HCC + lane * 4);
#pragma unroll
        for (int j = 0; j < 8; ++j) {
            float lj = fmaxf(l[j], NEG_SLOPE * l[j]);
            float p = __expf(lj);
            s += p;
            acc0 = fmaf(p, bf2f(xv[j].x), acc0);
            acc1 = fmaf(p, bf2f(xv[j].y), acc1);
            acc2 = fmaf(p, bf2f(xv[j].z), acc2);
            acc3 = fmaf(p, bf2f(xv[j].w), acc3);
        }
    }
    for (; e + 4 <= s1; e += 4) {
        int idx[4];
#pragma unroll
        for (int j = 0; j < 4; ++j) idx[j] = eid[e + j];
        float l[4];
#pragma unroll
        for (int j = 0; j < 4; ++j) l[j] = a_s[(size_t)idx[j] * HEADS + h] + adn;
        ushort4 xv[4];
#pragma unroll
        for (int j = 0; j < 4; ++j)
            xv[j] = *(const ushort4*)(XLB + (size_t)idx[j] * HCC + lane * 4);
#pragma unroll
        for (int j = 0; j < 4; ++j) {
            float lj = fmaxf(l[j], NEG_SLOPE * l[j]);
            float p = __expf(lj);
            s += p;
            acc0 = fmaf(p, bf2f(xv[j].x), acc0);
            acc1 = fmaf(p, bf2f(xv[j].y), acc1);
            acc2 = fmaf(p, bf2f(xv[j].z), acc2);
            acc3 = fmaf(p, bf2f(xv[j].w), acc3);
        }
    }
    for (; e < s1; ++e) {
        int src = eid[e];
        float l = a_s[(size_t)src * HEADS + h] + adn;
        l = fmaxf(l, NEG_SLOPE * l);
        float p = __expf(l);
        ushort4 xv = *(const ushort4*)(XLB + (size_t)src * HCC + lane * 4);
        s += p;
        acc0 = fmaf(p, bf2f(xv.x), acc0);
        acc1 = fmaf(p, bf2f(xv.y), acc1);
        acc2 = fmaf(p, bf2f(xv.z), acc2);
        acc3 = fmaf(p, bf2f(xv.w), acc3);
    }

    float inv = 1.f / (s + 1e-16f);
    float4 b = *(const float4*)(BIAS + lane * 4);
    float4 o;
    o.x = acc0 * inv + b.x;
    o.y = acc1 * inv + b.y;
    o.z = acc2 * inv + b.z;
    o.w = acc3 * inv + b.w;
    *(float4*)(OUT + (size_t)n * HCC + lane * 4) = o;
}

// ---------------------------------------------------------------------------
extern "C" void kernel_launch(void* const* d_in, const int* in_sizes, int n_in,
                              void* d_out, int out_size, void* d_ws,
                              size_t ws_size, hipStream_t stream) {
    const float* X = (const float*)d_in[0];
    const int* EI = (const int*)d_in[1];
    const float* W = (const float*)d_in[2];
    const float* ASRC = (const float*)d_in[3];
    const float* ADST = (const float*)d_in[4];
    const float* BIAS = (const float*)d_in[5];
    float* OUT = (float*)d_out;

    const int N = in_sizes[0] / IN_CH;
    const int E = in_sizes[1] / 2;
    const int ET = E + N;
    const int rng = (N + NBUK - 1) / NBUK;
    const unsigned M = (unsigned)(((1ULL << 32) + rng - 1) / (unsigned)rng);

    // workspace layout (all 256B aligned)
    char* w = (char*)d_ws;
    auto align = [](size_t x) { return (x + 255) & ~(size_t)255; };
    size_t o = 0;
    unsigned short* xlb = (unsigned short*)(w + o); o += align((size_t)N * HCC * 2);
    unsigned short* xb = (unsigned short*)(w + o);  o += align((size_t)N * IN_CH * 2);
    unsigned short* wt = (unsigned short*)(w + o);  o += align((size_t)IN_CH * HCC * 2);
    float* a_s = (float*)(w + o); o += align((size_t)N * HEADS * 4);
    float* a_d = (float*)(w + o); o += align((size_t)N * HEADS * 4);
    int* rowptr = (int*)(w + o);  o += align((size_t)(N + 1) * 4);
    int* eid = (int*)(w + o);     o += align((size_t)ET * 4);
    unsigned* pedges = (unsigned*)(w + o); o += align((size_t)E * 4);
    int* pcnt2d = (int*)(w + o);  o += align((size_t)NBUK * NBLK * 4);
    int* base2d = (int*)(w + o);  o += align((size_t)NBUK * NBLK * 4);
    int* pbase = (int*)(w + o);   o += align((NBUK + 1) * 4);

    // 0. W -> WT (bf16, transposed); X -> bf16 || CSR histogram (fused)
    k_wt<<<HCC, IN_CH, 0, stream>>>(W, wt);
    long nquad = (long)N * IN_CH / 4;
    int gxb = (int)((nquad + 255) / 256);
    if (gxb > 2048) gxb = 2048;
    k_xb_pcnt<<<gxb + NBLK, 256, 0, stream>>>(X, xb, nquad, gxb, EI, pcnt2d,
                                              E, M);

    // 1. persistent GEMM (W resident in LDS, +att logits)
    int ntiles = (N + 31) / 32;
    k_gemm_pers<<<256, 512, 0, stream>>>(xb, wt, ASRC, ADST, xlb, a_s, a_d,
                                         N, ntiles);

    // 2. CSR build v6.2
    k_pscan<<<1, 1024, 0, stream>>>(pcnt2d, base2d, pbase, E);
    k_part2<<<NBLK, 256, 0, stream>>>(EI, base2d, pedges, E, M, rng);
    k_fin<<<NBUK, 256, 0, stream>>>(pbase, pedges, rowptr, eid, N, rng);

    // 3. per-dst softmax + weighted aggregation (one wave per node)
    k_agg<<<(N + 3) / 4, 256, 0, stream>>>(rowptr, eid, a_s, a_d, xlb, BIAS,
                                           OUT, N);
}